// Round 4
// baseline (459.658 us; speedup 1.0000x reference)
//
#include <hip/hip_runtime.h>

typedef unsigned short u16;
typedef __attribute__((ext_vector_type(8))) short short8v;
typedef __attribute__((ext_vector_type(4))) float floatx4;

#define B_ 16
#define C_ 512
#define N_ 4096
#define K_ 128   // keys
#define NT 64    // pixels per block

__device__ __forceinline__ float bf2f(u16 u) {
    unsigned int x = ((unsigned int)u) << 16;
    return __builtin_bit_cast(float, x);
}
__device__ __forceinline__ u16 f2bf(float f) {
    unsigned int u = __builtin_bit_cast(unsigned int, f);
    u = u + 0x7FFFu + ((u >> 16) & 1u);
    return (u16)(u >> 16);
}

// ---------------------------------------------------------------------------
// P0: fp32 -> bf16 converts (y1,y2,wk1,wk2,wv1,wv2) + wq transpose, one launch
// ---------------------------------------------------------------------------
__global__ void conv_all(const float* __restrict__ y1, const float* __restrict__ y2,
                         const float* __restrict__ wk1, const float* __restrict__ wk2,
                         const float* __restrict__ wv1, const float* __restrict__ wv2,
                         const float* __restrict__ wq1, const float* __restrict__ wq2,
                         u16* y1b, u16* y2b, u16* wk1b, u16* wk2b, u16* wv1b, u16* wv2b,
                         u16* wq1t, u16* wq2t) {
    int tid = blockIdx.x * 256 + threadIdx.x;
    const int SY = B_ * K_ * C_;        // 1048576
    const int SWK = 256 * 512;          // 131072
    const int SWV = 512 * 512;          // 262144
    const int SQ = 128 * 512;           // 65536
    int base = 2*SY + 2*SWK + 2*SWV;
    if (tid < base) {
        const float* src; u16* dst; int off;
        if (tid < SY)                 { src = y1;  dst = y1b;  off = tid; }
        else if (tid < 2*SY)          { src = y2;  dst = y2b;  off = tid - SY; }
        else if (tid < 2*SY+SWK)      { src = wk1; dst = wk1b; off = tid - 2*SY; }
        else if (tid < 2*SY+2*SWK)    { src = wk2; dst = wk2b; off = tid - 2*SY - SWK; }
        else if (tid < 2*SY+2*SWK+SWV){ src = wv1; dst = wv1b; off = tid - 2*SY - 2*SWK; }
        else                          { src = wv2; dst = wv2b; off = tid - 2*SY - 2*SWK - SWV; }
        dst[off] = f2bf(src[off]);
    } else {
        int e = tid - base;           // 0 .. 2*SQ-1
        const float* s = (e >= SQ) ? wq2 : wq1;
        u16* d = (e >= SQ) ? wq2t : wq1t;
        e &= (SQ - 1);
        int dd = e >> 9;              // 0..127
        int c = e & 511;              // coalesced read over c
        d[c * 128 + dd] = f2bf(s[dd * 512 + c]);
    }
}

// ---------------------------------------------------------------------------
// P1: k1b/k2b [b][key][256] = y @ wk^T + bk  AND  vt1/vt2 [b][c][128] = (y@wv^T+bv)^T
// flat grid 768 blocks x 64 threads
// ---------------------------------------------------------------------------
__global__ void gemm_gkgv(const u16* __restrict__ y1b, const u16* __restrict__ y2b,
                          const u16* __restrict__ wk1b, const u16* __restrict__ wk2b,
                          const u16* __restrict__ wv1b, const u16* __restrict__ wv2b,
                          const float* __restrict__ bk1, const float* __restrict__ bk2,
                          const float* __restrict__ bv1, const float* __restrict__ bv2,
                          u16* k1b, u16* k2b, u16* vt1, u16* vt2) {
    int l = threadIdx.x;
    int id = blockIdx.x;
    const u16 *A, *Bt; const float* bias; u16* outp;
    int m0, n0, po; bool bias_m;
    if (id < 256) {
        int bx = id & 1, by = (id >> 1) & 3, z = id >> 3;
        int b = z >> 1, which = z & 1;
        A = (which ? y2b : y1b) + (size_t)b * K_ * C_;
        Bt = which ? wk2b : wk1b;
        bias = which ? bk2 : bk1;
        outp = (which ? k2b : k1b) + (size_t)b * K_ * 256;
        m0 = bx * 64; n0 = by * 64; po = 256; bias_m = false;
    } else {
        int id2 = id - 256;
        int bx = id2 & 7, by = (id2 >> 3) & 1, z = id2 >> 4;
        int b = z >> 1, which = z & 1;
        A = which ? wv2b : wv1b;
        Bt = (which ? y2b : y1b) + (size_t)b * K_ * C_;
        bias = which ? bv2 : bv1;
        outp = (which ? vt2 : vt1) + (size_t)b * C_ * K_;
        m0 = bx * 64; n0 = by * 64; po = 128; bias_m = true;
    }
    floatx4 acc[4][4] = {};
    for (int ch = 0; ch < 16; ++ch) {
        int koff = ch * 32 + (l >> 4) * 8;
        short8v a[4], wv[4];
#pragma unroll
        for (int mf = 0; mf < 4; ++mf) a[mf] = *(const short8v*)(A + (size_t)(m0 + mf*16 + (l & 15)) * 512 + koff);
#pragma unroll
        for (int nf = 0; nf < 4; ++nf) wv[nf] = *(const short8v*)(Bt + (size_t)(n0 + nf*16 + (l & 15)) * 512 + koff);
#pragma unroll
        for (int mf = 0; mf < 4; ++mf)
#pragma unroll
            for (int nf = 0; nf < 4; ++nf)
                acc[mf][nf] = __builtin_amdgcn_mfma_f32_16x16x32_bf16(a[mf], wv[nf], acc[mf][nf], 0, 0, 0);
    }
#pragma unroll
    for (int mf = 0; mf < 4; ++mf)
#pragma unroll
        for (int nf = 0; nf < 4; ++nf)
#pragma unroll
            for (int rg = 0; rg < 4; ++rg) {
                int m = m0 + mf*16 + (l >> 4)*4 + rg;
                int n = n0 + nf*16 + (l & 15);
                outp[(size_t)m * po + n] = f2bf(acc[mf][nf][rg] + (bias_m ? bias[m] : bias[n]));
            }
}

// ---------------------------------------------------------------------------
// P2: kd = k1b - k2b  (bf16), 524288 elems
// ---------------------------------------------------------------------------
__global__ void kd_sub(const u16* __restrict__ k1b, const u16* __restrict__ k2b,
                       u16* kd) {
    int tid = blockIdx.x * 256 + threadIdx.x;
    kd[tid] = f2bf(bf2f(k1b[tid]) - bf2f(k2b[tid]));
}

// P2b: ebd[b*128+key] = bq_cat . kd_row
__global__ void ebd_k(const u16* __restrict__ kd,
                      const float* __restrict__ bq1, const float* __restrict__ bq2,
                      float* ebd) {
    int tid = blockIdx.x * 256 + threadIdx.x;  // 2048
    const u16* kb = kd + (size_t)tid * 256;
    float s = 0.f;
    for (int d = 0; d < 128; ++d) s += bq1[d] * bf2f(kb[d]);
    for (int d = 0; d < 128; ++d) s += bq2[d] * bf2f(kb[128 + d]);
    ebd[tid] = s;
}

// ---------------------------------------------------------------------------
// P3: kkd1/kkd2 [b][key][512] bf16 = kd_half @ wqt^T (K=128 over d)
// grid (2, 8, 32) block 64; z = b*2 + which
// ---------------------------------------------------------------------------
__global__ void gemm_gkk(const u16* __restrict__ kd,
                         const u16* __restrict__ wq1t, const u16* __restrict__ wq2t,
                         u16* kkd1, u16* kkd2) {
    int l = threadIdx.x;
    int z = blockIdx.z; int b = z >> 1; int which = z & 1;
    const u16* A = kd + (size_t)b * K_ * 256 + which * 128;
    const u16* Wt = which ? wq2t : wq1t;
    u16* outp = (which ? kkd2 : kkd1) + (size_t)b * K_ * C_;
    int m0 = blockIdx.x * 64, n0 = blockIdx.y * 64;
    floatx4 acc[4][4] = {};
    for (int ch = 0; ch < 4; ++ch) {
        int koff = ch * 32 + (l >> 4) * 8;
        short8v a[4], wv[4];
#pragma unroll
        for (int mf = 0; mf < 4; ++mf) a[mf] = *(const short8v*)(A + (size_t)(m0 + mf*16 + (l & 15)) * 256 + koff);
#pragma unroll
        for (int nf = 0; nf < 4; ++nf) wv[nf] = *(const short8v*)(Wt + (size_t)(n0 + nf*16 + (l & 15)) * 128 + koff);
#pragma unroll
        for (int mf = 0; mf < 4; ++mf)
#pragma unroll
            for (int nf = 0; nf < 4; ++nf)
                acc[mf][nf] = __builtin_amdgcn_mfma_f32_16x16x32_bf16(a[mf], wv[nf], acc[mf][nf], 0, 0, 0);
    }
#pragma unroll
    for (int mf = 0; mf < 4; ++mf)
#pragma unroll
        for (int nf = 0; nf < 4; ++nf)
#pragma unroll
            for (int rg = 0; rg < 4; ++rg) {
                int m = m0 + mf*16 + (l >> 4)*4 + rg;
                int n = n0 + nf*16 + (l & 15);
                outp[(size_t)m * C_ + n] = f2bf(acc[mf][nf][rg]);
            }
}

// ---------------------------------------------------------------------------
// Main fused kernel, 8-wave / 512-thread blocks for 2x occupancy (target <=128 VGPR).
// E: per wave 32 rows x 32 keys (ed[2][2]); PV: per wave-step 16 c x 64 n (o[4]).
// grid 1024, block 512.
// ---------------------------------------------------------------------------
__global__ __launch_bounds__(512, 4)
void main_attn(const float* __restrict__ x1, const float* __restrict__ x2,
               const u16* __restrict__ kkd1, const u16* __restrict__ kkd2,
               const u16* __restrict__ vt1, const u16* __restrict__ vt2,
               const float* __restrict__ ebd,
               const float* __restrict__ scale_p,
               float* __restrict__ out1, float* __restrict__ out2) {
    __shared__ u16 xTb[2][4096];      // 16KB: [64 n][64 c] bf16, swizzled, double-buffered
    __shared__ u16 attn_s[8192];      // 16KB: [64 n][128 k] bf16, swizzled
    __shared__ float redA[256];       // [4 kgroup][64 row]
    __shared__ float redM[64];

    int bid0 = blockIdx.x;
    int bid = ((bid0 & 7) << 7) | (bid0 >> 3);   // XCD swizzle (1024 = 8*128, bijective)
    int b = bid >> 6;
    int n0 = (bid & 63) * NT;
    int t = threadIdx.x;
    int w = t >> 6;       // 0..7
    int l = t & 63;
    int nh = w >> 2;      // n-half: rows nh*32..nh*32+31
    int kg = w & 3;       // key group: keys kg*32..kg*32+31

    const float sc = scale_p[0];
    const float* xs0 = x1 + (size_t)b * C_ * N_;
    const float* xs1 = x2 + (size_t)b * C_ * N_;
    const u16* kkp[2] = { kkd1 + (size_t)b * K_ * C_, kkd2 + (size_t)b * K_ * C_ };

    floatx4 ed[2][2] = {};            // [mf][kf]: rows nh*32+mf*16+.., keys kg*32+kf*16+..

    float xA[8], xB[8];
    short8v kkA[2][2], kkB[2][2];     // [kf][ch]

    // staging: thread covers c-granule w (8 channels), pixel l
    auto LOADX = [&](int r, float (&v)[8]) {
        const float* xp = (r >= 8 ? xs1 : xs0) + (size_t)((r & 7) * 64 + w * 8) * N_ + n0 + l;
#pragma unroll
        for (int j = 0; j < 8; ++j) v[j] = xp[(size_t)j * N_];
    };
    auto WRITEXT = [&](u16* xbuf, float (&v)[8]) {
        short8v p;
#pragma unroll
        for (int j = 0; j < 8; ++j) p[j] = (short)f2bf(v[j]);
        *(short8v*)&xbuf[l * 64 + 8 * (w ^ (l & 7))] = p;
    };
    auto LOADK = [&](int r, short8v (&kkf)[2][2]) {
        const u16* base = kkp[r >> 3] + (size_t)(kg * 32 + (l & 15)) * 512 + (r & 7) * 64 + (l >> 4) * 8;
#pragma unroll
        for (int kf = 0; kf < 2; ++kf)
#pragma unroll
            for (int ch = 0; ch < 2; ++ch)
                kkf[kf][ch] = *(const short8v*)(base + kf * 16 * 512 + ch * 32);
    };
    auto EMM = [&](const u16* xbuf, short8v (&kkf)[2][2]) {
#pragma unroll
        for (int ch = 0; ch < 2; ++ch) {
            short8v a[2];
#pragma unroll
            for (int mf = 0; mf < 2; ++mf) {
                int row = nh * 32 + mf * 16 + (l & 15);
                int g = ch * 4 + (l >> 4);
                a[mf] = *(const short8v*)&xbuf[row * 64 + 8 * (g ^ (row & 7))];
            }
#pragma unroll
            for (int kf = 0; kf < 2; ++kf)
#pragma unroll
                for (int mf = 0; mf < 2; ++mf)
                    ed[mf][kf] = __builtin_amdgcn_mfma_f32_16x16x32_bf16(a[mf], kkf[kf][ch], ed[mf][kf], 0, 0, 0);
        }
    };

    // ---- E phase: 16 rounds of 64 channels, 1 barrier/round, 1-round prefetch
    LOADX(0, xA); LOADK(0, kkA);
    WRITEXT(xTb[0], xA);
    LOADX(1, xB); LOADK(1, kkB);
#pragma unroll
    for (int rr = 0; rr < 8; ++rr) {
        int rA = 2 * rr, rB = 2 * rr + 1;
        __syncthreads();
        EMM(xTb[0], kkA);                      // round rA
        WRITEXT(xTb[1], xB);
        if (rA + 2 <= 15) { LOADX(rA + 2, xA); LOADK(rA + 2, kkA); }
        __syncthreads();
        EMM(xTb[1], kkB);                      // round rB
        if (rB + 1 <= 15) WRITEXT(xTb[0], xA);
        if (rB + 2 <= 15) { LOADX(rB + 2, xB); LOADK(rB + 2, kkB); }
    }

    // ---- softmax over keys of |ediff + ebd|
    float ebdv[2];
#pragma unroll
    for (int kf = 0; kf < 2; ++kf) ebdv[kf] = ebd[b * 128 + kg * 32 + kf * 16 + (l & 15)];
#pragma unroll
    for (int mf = 0; mf < 2; ++mf)
#pragma unroll
        for (int kf = 0; kf < 2; ++kf)
#pragma unroll
            for (int rg = 0; rg < 4; ++rg)
                ed[mf][kf][rg] = fabsf(ed[mf][kf][rg] + ebdv[kf]);

    float m8[8];
#pragma unroll
    for (int mf = 0; mf < 2; ++mf)
#pragma unroll
        for (int rg = 0; rg < 4; ++rg)
            m8[mf * 4 + rg] = fmaxf(ed[mf][0][rg], ed[mf][1][rg]);
#pragma unroll
    for (int st = 1; st < 16; st <<= 1)
#pragma unroll
        for (int i = 0; i < 8; ++i)
            m8[i] = fmaxf(m8[i], __shfl_xor(m8[i], st));
    if ((l & 15) == 0) {
#pragma unroll
        for (int mf = 0; mf < 2; ++mf)
#pragma unroll
            for (int rg = 0; rg < 4; ++rg)
                redA[kg * 64 + nh * 32 + mf * 16 + (l >> 4) * 4 + rg] = m8[mf * 4 + rg];
    }
    __syncthreads();
    if (t < 64) redM[t] = fmaxf(fmaxf(redA[t], redA[64 + t]), fmaxf(redA[128 + t], redA[192 + t]));
    __syncthreads();

    float s8[8];
#pragma unroll
    for (int mf = 0; mf < 2; ++mf)
#pragma unroll
        for (int rg = 0; rg < 4; ++rg) {
            float mr = redM[nh * 32 + mf * 16 + (l >> 4) * 4 + rg];
            float e0 = __expf(ed[mf][0][rg] - mr);
            float e1 = __expf(ed[mf][1][rg] - mr);
            ed[mf][0][rg] = e0; ed[mf][1][rg] = e1;
            s8[mf * 4 + rg] = e0 + e1;
        }
#pragma unroll
    for (int st = 1; st < 16; st <<= 1)
#pragma unroll
        for (int i = 0; i < 8; ++i)
            s8[i] += __shfl_xor(s8[i], st);
    if ((l & 15) == 0) {
#pragma unroll
        for (int mf = 0; mf < 2; ++mf)
#pragma unroll
            for (int rg = 0; rg < 4; ++rg)
                redA[kg * 64 + nh * 32 + mf * 16 + (l >> 4) * 4 + rg] = s8[mf * 4 + rg];
    }
    __syncthreads();
    if (t < 64) redM[t] = redA[t] + redA[64 + t] + redA[128 + t] + redA[192 + t];
    __syncthreads();

#pragma unroll
    for (int mf = 0; mf < 2; ++mf)
#pragma unroll
        for (int rg = 0; rg < 4; ++rg) {
            int row = nh * 32 + mf * 16 + (l >> 4) * 4 + rg;
            float inv = 1.0f / redM[row];
#pragma unroll
            for (int kf = 0; kf < 2; ++kf) {
                int col = kg * 32 + kf * 16 + (l & 15);
                attn_s[row * 128 + 8 * ((col >> 3) ^ (row & 7)) + (col & 7)] = f2bf(ed[mf][kf][rg] * inv);
            }
        }
    __syncthreads();

    // ---- PV: O[c][n] = vt[c][k] . attn[n][k], + residual. wave w: out oi = w>>2, c-group (w&3)*128
    {
        int oi = w >> 2, cg = w & 3;
        const u16* vt = (oi ? vt2 : vt1) + (size_t)b * C_ * K_;
        const float* xr = oi ? xs1 : xs0;
        float* op = (oi ? out2 : out1) + (size_t)b * C_ * N_;

        short8v vfA[4], vfB[4];
        float rsA[4][4], rsB[4][4];
        auto LOADPV = [&](int step, short8v (&vf)[4], float (&rs)[4][4]) {
            int cr = cg * 128 + step * 16;
            const u16* vp = vt + (size_t)(cr + (l & 15)) * K_ + (l >> 4) * 8;
#pragma unroll
            for (int kc = 0; kc < 4; ++kc) vf[kc] = *(const short8v*)(vp + kc * 32);
            const float* rp = xr + (size_t)(cr + (l >> 4) * 4) * N_ + n0 + (l & 15);
#pragma unroll
            for (int rg = 0; rg < 4; ++rg)
#pragma unroll
                for (int nf = 0; nf < 4; ++nf)
                    rs[rg][nf] = rp[(size_t)rg * N_ + nf * 16];
        };
        auto COMPPV = [&](int step, short8v (&vf)[4], float (&rs)[4][4]) {
            floatx4 o[4] = {};
#pragma unroll
            for (int kc = 0; kc < 4; ++kc) {
                short8v bb[4];
#pragma unroll
                for (int nf = 0; nf < 4; ++nf) {
                    int nrow = nf * 16 + (l & 15);
                    int g = kc * 4 + (l >> 4);
                    bb[nf] = *(const short8v*)&attn_s[nrow * 128 + 8 * (g ^ (nrow & 7))];
                }
#pragma unroll
                for (int nf = 0; nf < 4; ++nf)
                    o[nf] = __builtin_amdgcn_mfma_f32_16x16x32_bf16(vf[kc], bb[nf], o[nf], 0, 0, 0);
            }
            int cr = cg * 128 + step * 16 + (l >> 4) * 4;
#pragma unroll
            for (int rg = 0; rg < 4; ++rg)
#pragma unroll
                for (int nf = 0; nf < 4; ++nf) {
                    size_t idx = (size_t)(cr + rg) * N_ + n0 + nf * 16 + (l & 15);
                    op[idx] = sc * o[nf][rg] + rs[rg][nf];
                }
        };

        LOADPV(0, vfA, rsA);
        LOADPV(1, vfB, rsB);
#pragma unroll
        for (int ss = 0; ss < 4; ++ss) {
            COMPPV(2 * ss, vfA, rsA);
            if (2 * ss + 2 < 8) LOADPV(2 * ss + 2, vfA, rsA);
            COMPPV(2 * ss + 1, vfB, rsB);
            if (2 * ss + 3 < 8) LOADPV(2 * ss + 3, vfB, rsB);
        }
    }
}

// ---------------------------------------------------------------------------
extern "C" void kernel_launch(void* const* d_in, const int* in_sizes, int n_in,
                              void* d_out, int out_size, void* d_ws, size_t ws_size,
                              hipStream_t stream) {
    const float* x1 = (const float*)d_in[0];
    const float* y1 = (const float*)d_in[1];
    const float* x2 = (const float*)d_in[2];
    const float* y2 = (const float*)d_in[3];
    const float* wq1 = (const float*)d_in[4];
    const float* bq1 = (const float*)d_in[5];
    const float* wq2 = (const float*)d_in[6];
    const float* bq2 = (const float*)d_in[7];
    const float* wk1 = (const float*)d_in[8];
    const float* bk1 = (const float*)d_in[9];
    const float* wk2 = (const float*)d_in[10];
    const float* bk2 = (const float*)d_in[11];
    const float* wv1 = (const float*)d_in[12];
    const float* bv1 = (const float*)d_in[13];
    const float* wv2 = (const float*)d_in[14];
    const float* bv2 = (const float*)d_in[15];
    const float* scale = (const float*)d_in[16];

    char* ws = (char*)d_ws;
    u16* y1b  = (u16*)(ws + 0);
    u16* y2b  = (u16*)(ws + 2097152);
    u16* wk1b = (u16*)(ws + 4194304);
    u16* wk2b = (u16*)(ws + 4456448);
    u16* wv1b = (u16*)(ws + 4718592);
    u16* wv2b = (u16*)(ws + 5242880);
    u16* wq1t = (u16*)(ws + 5767168);
    u16* wq2t = (u16*)(ws + 5898240);
    u16* k1b  = (u16*)(ws + 6029312);
    u16* k2b  = (u16*)(ws + 7077888);
    u16* kd   = (u16*)(ws + 8126464);
    u16* kkd1 = (u16*)(ws + 9175040);
    u16* kkd2 = (u16*)(ws + 11272192);
    u16* vt1  = (u16*)(ws + 13369344);
    u16* vt2  = (u16*)(ws + 15466496);
    float* ebd = (float*)(ws + 17563648);

    float* out1 = (float*)d_out;
    float* out2 = out1 + (size_t)B_ * C_ * N_;

    hipLaunchKernelGGL(conv_all, dim3(11776), dim3(256), 0, stream,
                       y1, y2, wk1, wk2, wv1, wv2, wq1, wq2,
                       y1b, y2b, wk1b, wk2b, wv1b, wv2b, wq1t, wq2t);
    hipLaunchKernelGGL(gemm_gkgv, dim3(768), dim3(64), 0, stream,
                       y1b, y2b, wk1b, wk2b, wv1b, wv2b, bk1, bk2, bv1, bv2,
                       k1b, k2b, vt1, vt2);
    hipLaunchKernelGGL(kd_sub, dim3(2048), dim3(256), 0, stream, k1b, k2b, kd);
    hipLaunchKernelGGL(ebd_k, dim3(8), dim3(256), 0, stream, kd, bq1, bq2, ebd);
    hipLaunchKernelGGL(gemm_gkk, dim3(2, 8, 32), dim3(64), 0, stream,
                       kd, wq1t, wq2t, kkd1, kkd2);
    hipLaunchKernelGGL(main_attn, dim3(1024), dim3(512), 0, stream,
                       x1, x2, kkd1, kkd2, vt1, vt2, ebd, scale,
                       out1, out2);
}

// Round 5
// 287.139 us; speedup vs baseline: 1.6008x; 1.6008x over previous
//
#include <hip/hip_runtime.h>

typedef unsigned short u16;
typedef __attribute__((ext_vector_type(8))) short short8v;
typedef __attribute__((ext_vector_type(4))) short short4v;
typedef __attribute__((ext_vector_type(4))) float floatx4;

#define B_ 16
#define C_ 512
#define N_ 4096
#define K_ 128   // keys
#define NT 32    // pixels per block

__device__ __forceinline__ float bf2f(u16 u) {
    unsigned int x = ((unsigned int)u) << 16;
    return __builtin_bit_cast(float, x);
}
__device__ __forceinline__ u16 f2bf(float f) {
    unsigned int u = __builtin_bit_cast(unsigned int, f);
    u = u + 0x7FFFu + ((u >> 16) & 1u);
    return (u16)(u >> 16);
}

// ---------------------------------------------------------------------------
// P0: fp32 -> bf16 converts (y1,y2,wk1,wk2,wv1,wv2) + wq transpose, one launch
// ---------------------------------------------------------------------------
__global__ void conv_all(const float* __restrict__ y1, const float* __restrict__ y2,
                         const float* __restrict__ wk1, const float* __restrict__ wk2,
                         const float* __restrict__ wv1, const float* __restrict__ wv2,
                         const float* __restrict__ wq1, const float* __restrict__ wq2,
                         u16* y1b, u16* y2b, u16* wk1b, u16* wk2b, u16* wv1b, u16* wv2b,
                         u16* wq1t, u16* wq2t) {
    int tid = blockIdx.x * 256 + threadIdx.x;
    const int SY = B_ * K_ * C_;        // 1048576
    const int SWK = 256 * 512;          // 131072
    const int SWV = 512 * 512;          // 262144
    const int SQ = 128 * 512;           // 65536
    int base = 2*SY + 2*SWK + 2*SWV;
    if (tid < base) {
        const float* src; u16* dst; int off;
        if (tid < SY)                 { src = y1;  dst = y1b;  off = tid; }
        else if (tid < 2*SY)          { src = y2;  dst = y2b;  off = tid - SY; }
        else if (tid < 2*SY+SWK)      { src = wk1; dst = wk1b; off = tid - 2*SY; }
        else if (tid < 2*SY+2*SWK)    { src = wk2; dst = wk2b; off = tid - 2*SY - SWK; }
        else if (tid < 2*SY+2*SWK+SWV){ src = wv1; dst = wv1b; off = tid - 2*SY - 2*SWK; }
        else                          { src = wv2; dst = wv2b; off = tid - 2*SY - 2*SWK - SWV; }
        dst[off] = f2bf(src[off]);
    } else {
        int e = tid - base;           // 0 .. 2*SQ-1
        const float* s = (e >= SQ) ? wq2 : wq1;
        u16* d = (e >= SQ) ? wq2t : wq1t;
        e &= (SQ - 1);
        int dd = e >> 9;              // 0..127
        int c = e & 511;              // coalesced read over c
        d[c * 128 + dd] = f2bf(s[dd * 512 + c]);
    }
}

// ---------------------------------------------------------------------------
// P1: k1b/k2b [b][key][256] = y @ wk^T + bk  AND  vt1/vt2 [b][c][128] = (y@wv^T+bv)^T
// flat grid 768 blocks x 64 threads
// ---------------------------------------------------------------------------
__global__ void gemm_gkgv(const u16* __restrict__ y1b, const u16* __restrict__ y2b,
                          const u16* __restrict__ wk1b, const u16* __restrict__ wk2b,
                          const u16* __restrict__ wv1b, const u16* __restrict__ wv2b,
                          const float* __restrict__ bk1, const float* __restrict__ bk2,
                          const float* __restrict__ bv1, const float* __restrict__ bv2,
                          u16* k1b, u16* k2b, u16* vt1, u16* vt2) {
    int l = threadIdx.x;
    int id = blockIdx.x;
    const u16 *A, *Bt; const float* bias; u16* outp;
    int m0, n0, po; bool bias_m;
    if (id < 256) {
        int bx = id & 1, by = (id >> 1) & 3, z = id >> 3;
        int b = z >> 1, which = z & 1;
        A = (which ? y2b : y1b) + (size_t)b * K_ * C_;
        Bt = which ? wk2b : wk1b;
        bias = which ? bk2 : bk1;
        outp = (which ? k2b : k1b) + (size_t)b * K_ * 256;
        m0 = bx * 64; n0 = by * 64; po = 256; bias_m = false;
    } else {
        int id2 = id - 256;
        int bx = id2 & 7, by = (id2 >> 3) & 1, z = id2 >> 4;
        int b = z >> 1, which = z & 1;
        A = which ? wv2b : wv1b;
        Bt = (which ? y2b : y1b) + (size_t)b * K_ * C_;
        bias = which ? bv2 : bv1;
        outp = (which ? vt2 : vt1) + (size_t)b * C_ * K_;
        m0 = bx * 64; n0 = by * 64; po = 128; bias_m = true;
    }
    floatx4 acc[4][4] = {};
    for (int ch = 0; ch < 16; ++ch) {
        int koff = ch * 32 + (l >> 4) * 8;
        short8v a[4], wv[4];
#pragma unroll
        for (int mf = 0; mf < 4; ++mf) a[mf] = *(const short8v*)(A + (size_t)(m0 + mf*16 + (l & 15)) * 512 + koff);
#pragma unroll
        for (int nf = 0; nf < 4; ++nf) wv[nf] = *(const short8v*)(Bt + (size_t)(n0 + nf*16 + (l & 15)) * 512 + koff);
#pragma unroll
        for (int mf = 0; mf < 4; ++mf)
#pragma unroll
            for (int nf = 0; nf < 4; ++nf)
                acc[mf][nf] = __builtin_amdgcn_mfma_f32_16x16x32_bf16(a[mf], wv[nf], acc[mf][nf], 0, 0, 0);
    }
#pragma unroll
    for (int mf = 0; mf < 4; ++mf)
#pragma unroll
        for (int nf = 0; nf < 4; ++nf)
#pragma unroll
            for (int rg = 0; rg < 4; ++rg) {
                int m = m0 + mf*16 + (l >> 4)*4 + rg;
                int n = n0 + nf*16 + (l & 15);
                outp[(size_t)m * po + n] = f2bf(acc[mf][nf][rg] + (bias_m ? bias[m] : bias[n]));
            }
}

// ---------------------------------------------------------------------------
// P2: kd = k1b - k2b  (bf16), 524288 elems
// ---------------------------------------------------------------------------
__global__ void kd_sub(const u16* __restrict__ k1b, const u16* __restrict__ k2b,
                       u16* kd) {
    int tid = blockIdx.x * 256 + threadIdx.x;
    kd[tid] = f2bf(bf2f(k1b[tid]) - bf2f(k2b[tid]));
}

// P2b: ebd[b*128+key] = bq_cat . kd_row
__global__ void ebd_k(const u16* __restrict__ kd,
                      const float* __restrict__ bq1, const float* __restrict__ bq2,
                      float* ebd) {
    int tid = blockIdx.x * 256 + threadIdx.x;  // 2048
    const u16* kb = kd + (size_t)tid * 256;
    float s = 0.f;
    for (int d = 0; d < 128; ++d) s += bq1[d] * bf2f(kb[d]);
    for (int d = 0; d < 128; ++d) s += bq2[d] * bf2f(kb[128 + d]);
    ebd[tid] = s;
}

// ---------------------------------------------------------------------------
// P3: kkd1/kkd2 [b][key][512] bf16 = kd_half @ wqt^T (K=128 over d)
// grid (2, 8, 32) block 64; z = b*2 + which
// ---------------------------------------------------------------------------
__global__ void gemm_gkk(const u16* __restrict__ kd,
                         const u16* __restrict__ wq1t, const u16* __restrict__ wq2t,
                         u16* kkd1, u16* kkd2) {
    int l = threadIdx.x;
    int z = blockIdx.z; int b = z >> 1; int which = z & 1;
    const u16* A = kd + (size_t)b * K_ * 256 + which * 128;
    const u16* Wt = which ? wq2t : wq1t;
    u16* outp = (which ? kkd2 : kkd1) + (size_t)b * K_ * C_;
    int m0 = blockIdx.x * 64, n0 = blockIdx.y * 64;
    floatx4 acc[4][4] = {};
    for (int ch = 0; ch < 4; ++ch) {
        int koff = ch * 32 + (l >> 4) * 8;
        short8v a[4], wv[4];
#pragma unroll
        for (int mf = 0; mf < 4; ++mf) a[mf] = *(const short8v*)(A + (size_t)(m0 + mf*16 + (l & 15)) * 256 + koff);
#pragma unroll
        for (int nf = 0; nf < 4; ++nf) wv[nf] = *(const short8v*)(Wt + (size_t)(n0 + nf*16 + (l & 15)) * 128 + koff);
#pragma unroll
        for (int mf = 0; mf < 4; ++mf)
#pragma unroll
            for (int nf = 0; nf < 4; ++nf)
                acc[mf][nf] = __builtin_amdgcn_mfma_f32_16x16x32_bf16(a[mf], wv[nf], acc[mf][nf], 0, 0, 0);
    }
#pragma unroll
    for (int mf = 0; mf < 4; ++mf)
#pragma unroll
        for (int nf = 0; nf < 4; ++nf)
#pragma unroll
            for (int rg = 0; rg < 4; ++rg) {
                int m = m0 + mf*16 + (l >> 4)*4 + rg;
                int n = n0 + nf*16 + (l & 15);
                outp[(size_t)m * C_ + n] = f2bf(acc[mf][nf][rg]);
            }
}

// ---------------------------------------------------------------------------
// Main fused kernel: R3 structure (4 waves, depth-1 prefetch, 1 barrier/round,
// in-reg softmax, double-buffered PV) at NT=32 -> 2048 small blocks, low VGPR.
// ---------------------------------------------------------------------------
__global__ __launch_bounds__(256, 4)
void main_attn(const float* __restrict__ x1, const float* __restrict__ x2,
               const u16* __restrict__ kkd1, const u16* __restrict__ kkd2,
               const u16* __restrict__ vt1, const u16* __restrict__ vt2,
               const float* __restrict__ ebd,
               const float* __restrict__ scale_p,
               float* __restrict__ out1, float* __restrict__ out2) {
    __shared__ u16 xTb[2][2048];      // 8KB: [32 n][64 c] bf16, swizzled (16B granules), dbuf
    __shared__ u16 attn_s[4096];      // 8KB: [32 n][128 k] bf16, swizzled
    __shared__ float redA[128];       // [4 kgroup][32 row]
    __shared__ float redM[32];

    int bid0 = blockIdx.x;
    int bid = ((bid0 & 7) << 8) | (bid0 >> 3);   // XCD swizzle (2048 = 8*256, bijective)
    int b = bid >> 7;
    int n0 = (bid & 127) * NT;
    int t = threadIdx.x;
    int w = t >> 6;       // 0..3
    int l = t & 63;

    const float sc = scale_p[0];
    const float* xs0 = x1 + (size_t)b * C_ * N_;
    const float* xs1 = x2 + (size_t)b * C_ * N_;
    const u16* kkp[2] = { kkd1 + (size_t)b * K_ * C_, kkd2 + (size_t)b * K_ * C_ };

    floatx4 ed[2][2] = {};            // rows n: mf*16+(l>>4)*4+rg ; keys: w*32+kf*16+(l&15)

    float xA[8], xB[8];               // 4 channels x 2 pixels
    short8v kkA[2][2], kkB[2][2];     // [kf][ch]

    // thread covers channels cb..cb+3 (cb = w*16+(l>>4)*4), pixel pair 2*(l&15)
    auto LOADX = [&](int r, float (&v)[8]) {
        const float* xp = (r >= 8 ? xs1 : xs0)
            + (size_t)((r & 7) * 64 + w * 16 + (l >> 4) * 4) * N_ + n0 + 2 * (l & 15);
#pragma unroll
        for (int j = 0; j < 4; ++j) { float2 f = *(const float2*)(xp + (size_t)j * N_); v[2*j] = f.x; v[2*j+1] = f.y; }
    };
    auto WRITEXT = [&](u16* xbuf, float (&v)[8]) {
        short4v p0, p1;
#pragma unroll
        for (int j = 0; j < 4; ++j) { p0[j] = (short)f2bf(v[2*j]); p1[j] = (short)f2bf(v[2*j+1]); }
        int row0 = 2 * (l & 15), row1 = row0 + 1;
        int cb = w * 16 + (l >> 4) * 4;
        int g = cb >> 3, sub = cb & 7;
        *(short4v*)&xTb[0][0 + (xbuf - &xTb[0][0]) + row0 * 64 + 8 * (g ^ (row0 & 7)) + sub] = p0;
        *(short4v*)&xTb[0][0 + (xbuf - &xTb[0][0]) + row1 * 64 + 8 * (g ^ (row1 & 7)) + sub] = p1;
    };
    auto LOADK = [&](int r, short8v (&kkf)[2][2]) {
        const u16* base = kkp[r >> 3] + (size_t)(w * 32 + (l & 15)) * 512 + (r & 7) * 64 + (l >> 4) * 8;
#pragma unroll
        for (int kf = 0; kf < 2; ++kf)
#pragma unroll
            for (int ch = 0; ch < 2; ++ch)
                kkf[kf][ch] = *(const short8v*)(base + kf * 16 * 512 + ch * 32);
    };
    auto EMM = [&](const u16* xbuf, short8v (&kkf)[2][2]) {
#pragma unroll
        for (int ch = 0; ch < 2; ++ch) {
            short8v a[2];
#pragma unroll
            for (int mf = 0; mf < 2; ++mf) {
                int row = mf * 16 + (l & 15);
                int g = ch * 4 + (l >> 4);
                a[mf] = *(const short8v*)&xbuf[row * 64 + 8 * (g ^ (row & 7))];
            }
#pragma unroll
            for (int kf = 0; kf < 2; ++kf)
#pragma unroll
                for (int mf = 0; mf < 2; ++mf)
                    ed[mf][kf] = __builtin_amdgcn_mfma_f32_16x16x32_bf16(a[mf], kkf[kf][ch], ed[mf][kf], 0, 0, 0);
        }
    };

    // ---- E phase: 16 rounds of 64 channels, 1 barrier/round, 1-round prefetch
    LOADX(0, xA); LOADK(0, kkA);
    WRITEXT(xTb[0], xA);
    LOADX(1, xB); LOADK(1, kkB);
#pragma unroll
    for (int rr = 0; rr < 8; ++rr) {
        int rA = 2 * rr, rB = 2 * rr + 1;
        __syncthreads();
        EMM(xTb[0], kkA);                      // round rA
        WRITEXT(xTb[1], xB);
        if (rA + 2 <= 15) { LOADX(rA + 2, xA); LOADK(rA + 2, kkA); }
        __syncthreads();
        EMM(xTb[1], kkB);                      // round rB
        if (rB + 1 <= 15) WRITEXT(xTb[0], xA);
        if (rB + 2 <= 15) { LOADX(rB + 2, xB); LOADK(rB + 2, kkB); }
    }

    // ---- softmax over keys of |ediff + ebd|
    float ebdv[2];
#pragma unroll
    for (int kf = 0; kf < 2; ++kf) ebdv[kf] = ebd[b * 128 + w * 32 + kf * 16 + (l & 15)];
#pragma unroll
    for (int mf = 0; mf < 2; ++mf)
#pragma unroll
        for (int kf = 0; kf < 2; ++kf)
#pragma unroll
            for (int rg = 0; rg < 4; ++rg)
                ed[mf][kf][rg] = fabsf(ed[mf][kf][rg] + ebdv[kf]);

    float m8[8];
#pragma unroll
    for (int mf = 0; mf < 2; ++mf)
#pragma unroll
        for (int rg = 0; rg < 4; ++rg)
            m8[mf * 4 + rg] = fmaxf(ed[mf][0][rg], ed[mf][1][rg]);
#pragma unroll
    for (int st = 1; st < 16; st <<= 1)
#pragma unroll
        for (int i = 0; i < 8; ++i)
            m8[i] = fmaxf(m8[i], __shfl_xor(m8[i], st));
    if ((l & 15) == 0) {
#pragma unroll
        for (int mf = 0; mf < 2; ++mf)
#pragma unroll
            for (int rg = 0; rg < 4; ++rg)
                redA[w * 32 + mf * 16 + (l >> 4) * 4 + rg] = m8[mf * 4 + rg];
    }
    __syncthreads();
    if (t < 32) redM[t] = fmaxf(fmaxf(redA[t], redA[32 + t]), fmaxf(redA[64 + t], redA[96 + t]));
    __syncthreads();

    float s8[8];
#pragma unroll
    for (int mf = 0; mf < 2; ++mf)
#pragma unroll
        for (int rg = 0; rg < 4; ++rg) {
            float mr = redM[mf * 16 + (l >> 4) * 4 + rg];
            float e0 = __expf(ed[mf][0][rg] - mr);
            float e1 = __expf(ed[mf][1][rg] - mr);
            ed[mf][0][rg] = e0; ed[mf][1][rg] = e1;
            s8[mf * 4 + rg] = e0 + e1;
        }
#pragma unroll
    for (int st = 1; st < 16; st <<= 1)
#pragma unroll
        for (int i = 0; i < 8; ++i)
            s8[i] += __shfl_xor(s8[i], st);
    if ((l & 15) == 0) {
#pragma unroll
        for (int mf = 0; mf < 2; ++mf)
#pragma unroll
            for (int rg = 0; rg < 4; ++rg)
                redA[w * 32 + mf * 16 + (l >> 4) * 4 + rg] = s8[mf * 4 + rg];
    }
    __syncthreads();
    if (t < 32) redM[t] = redA[t] + redA[32 + t] + redA[64 + t] + redA[96 + t];
    __syncthreads();

#pragma unroll
    for (int mf = 0; mf < 2; ++mf)
#pragma unroll
        for (int rg = 0; rg < 4; ++rg) {
            int row = mf * 16 + (l >> 4) * 4 + rg;
            float inv = 1.0f / redM[row];
#pragma unroll
            for (int kf = 0; kf < 2; ++kf) {
                int col = w * 32 + kf * 16 + (l & 15);
                attn_s[row * 128 + 8 * ((col >> 3) ^ (row & 7)) + (col & 7)] = f2bf(ed[mf][kf][rg] * inv);
            }
        }
    __syncthreads();

    // ---- PV: 16 steps (2 outputs x 8 c-chunks), wave owns 16 c-rows/step; dbuf prefetch
    const u16* vt1p = vt1 + (size_t)b * C_ * K_;
    const u16* vt2p = vt2 + (size_t)b * C_ * K_;
    float* out1p = out1 + (size_t)b * C_ * N_;
    float* out2p = out2 + (size_t)b * C_ * N_;

    short8v vfA[4], vfB[4];
    float rsA[4][2], rsB[4][2];
    auto LOADPV = [&](int s, short8v (&vf)[4], float (&rs)[4][2]) {
        int oi = s >> 3;
        int cb = (s & 7) * 64 + w * 16;
        const u16* vt = oi ? vt2p : vt1p;
        const float* xr = oi ? xs1 : xs0;
        const u16* vp = vt + (size_t)(cb + (l & 15)) * K_ + (l >> 4) * 8;
#pragma unroll
        for (int kc = 0; kc < 4; ++kc) vf[kc] = *(const short8v*)(vp + kc * 32);
        const float* rp = xr + (size_t)(cb + (l >> 4) * 4) * N_ + n0 + (l & 15);
#pragma unroll
        for (int rg = 0; rg < 4; ++rg)
#pragma unroll
            for (int nf = 0; nf < 2; ++nf)
                rs[rg][nf] = rp[(size_t)rg * N_ + nf * 16];
    };
    auto COMPPV = [&](int s, short8v (&vf)[4], float (&rs)[4][2]) {
        floatx4 o[2] = {};
#pragma unroll
        for (int kc = 0; kc < 4; ++kc) {
            short8v bb[2];
#pragma unroll
            for (int nf = 0; nf < 2; ++nf) {
                int nrow = nf * 16 + (l & 15);
                int g = kc * 4 + (l >> 4);
                bb[nf] = *(const short8v*)&attn_s[nrow * 128 + 8 * (g ^ (nrow & 7))];
            }
#pragma unroll
            for (int nf = 0; nf < 2; ++nf)
                o[nf] = __builtin_amdgcn_mfma_f32_16x16x32_bf16(vf[kc], bb[nf], o[nf], 0, 0, 0);
        }
        int oi = s >> 3;
        int cb = (s & 7) * 64 + w * 16 + (l >> 4) * 4;
        float* op = oi ? out2p : out1p;
#pragma unroll
        for (int rg = 0; rg < 4; ++rg)
#pragma unroll
            for (int nf = 0; nf < 2; ++nf) {
                size_t idx = (size_t)(cb + rg) * N_ + n0 + nf * 16 + (l & 15);
                op[idx] = sc * o[nf][rg] + rs[rg][nf];
            }
    };

    LOADPV(0, vfA, rsA);
    LOADPV(1, vfB, rsB);
#pragma unroll
    for (int ss = 0; ss < 8; ++ss) {
        COMPPV(2 * ss, vfA, rsA);
        if (2 * ss + 2 < 16) LOADPV(2 * ss + 2, vfA, rsA);
        COMPPV(2 * ss + 1, vfB, rsB);
        if (2 * ss + 3 < 16) LOADPV(2 * ss + 3, vfB, rsB);
    }
}

// ---------------------------------------------------------------------------
extern "C" void kernel_launch(void* const* d_in, const int* in_sizes, int n_in,
                              void* d_out, int out_size, void* d_ws, size_t ws_size,
                              hipStream_t stream) {
    const float* x1 = (const float*)d_in[0];
    const float* y1 = (const float*)d_in[1];
    const float* x2 = (const float*)d_in[2];
    const float* y2 = (const float*)d_in[3];
    const float* wq1 = (const float*)d_in[4];
    const float* bq1 = (const float*)d_in[5];
    const float* wq2 = (const float*)d_in[6];
    const float* bq2 = (const float*)d_in[7];
    const float* wk1 = (const float*)d_in[8];
    const float* bk1 = (const float*)d_in[9];
    const float* wk2 = (const float*)d_in[10];
    const float* bk2 = (const float*)d_in[11];
    const float* wv1 = (const float*)d_in[12];
    const float* bv1 = (const float*)d_in[13];
    const float* wv2 = (const float*)d_in[14];
    const float* bv2 = (const float*)d_in[15];
    const float* scale = (const float*)d_in[16];

    char* ws = (char*)d_ws;
    u16* y1b  = (u16*)(ws + 0);
    u16* y2b  = (u16*)(ws + 2097152);
    u16* wk1b = (u16*)(ws + 4194304);
    u16* wk2b = (u16*)(ws + 4456448);
    u16* wv1b = (u16*)(ws + 4718592);
    u16* wv2b = (u16*)(ws + 5242880);
    u16* wq1t = (u16*)(ws + 5767168);
    u16* wq2t = (u16*)(ws + 5898240);
    u16* k1b  = (u16*)(ws + 6029312);
    u16* k2b  = (u16*)(ws + 7077888);
    u16* kd   = (u16*)(ws + 8126464);
    u16* kkd1 = (u16*)(ws + 9175040);
    u16* kkd2 = (u16*)(ws + 11272192);
    u16* vt1  = (u16*)(ws + 13369344);
    u16* vt2  = (u16*)(ws + 15466496);
    float* ebd = (float*)(ws + 17563648);

    float* out1 = (float*)d_out;
    float* out2 = out1 + (size_t)B_ * C_ * N_;

    hipLaunchKernelGGL(conv_all, dim3(11776), dim3(256), 0, stream,
                       y1, y2, wk1, wk2, wv1, wv2, wq1, wq2,
                       y1b, y2b, wk1b, wk2b, wv1b, wv2b, wq1t, wq2t);
    hipLaunchKernelGGL(gemm_gkgv, dim3(768), dim3(64), 0, stream,
                       y1b, y2b, wk1b, wk2b, wv1b, wv2b, bk1, bk2, bv1, bv2,
                       k1b, k2b, vt1, vt2);
    hipLaunchKernelGGL(kd_sub, dim3(2048), dim3(256), 0, stream, k1b, k2b, kd);
    hipLaunchKernelGGL(ebd_k, dim3(8), dim3(256), 0, stream, kd, bq1, bq2, ebd);
    hipLaunchKernelGGL(gemm_gkk, dim3(2, 8, 32), dim3(64), 0, stream,
                       kd, wq1t, wq2t, kkd1, kkd2);
    hipLaunchKernelGGL(main_attn, dim3(2048), dim3(256), 0, stream,
                       x1, x2, kkd1, kkd2, vt1, vt2, ebd, scale,
                       out1, out2);
}